// Round 20
// baseline (113.000 us; speedup 1.0000x reference)
//
#include <hip/hip_runtime.h>

// SSD MultiBoxLoss: B=64, P=29126, G=24, 2 classes, scalar fp32 output.
// z-space selection (CE = softplus(z) monotone => top-k set identical, sum
// tie-invariant). 4 launches: zero -> sparse -> count -> collect+select+final
// (per-batch tickets). 8 priors/thread for memory-level parallelism.
static constexpr int B_ = 64;
static constexpr int P_ = 29126;
static constexpr int G_ = 24;
static constexpr float THRESH_ = 0.35f;
static constexpr int NEGPOS_ = 7;
static constexpr int NCH_ = 15;                   // p-chunks of 2048
static constexpr int NBL_ = NCH_ * B_;            // 960 partial slots
static constexpr int WPB_ = 912;                  // bit-words/batch
static constexpr int CCS_ = 32;                   // counter stride = 128 B

// z-space ladder (must match literals in k_count exactly)
__device__ const float LAD_[16] = {
    -0.5f, -0.2f, 0.0f, 0.2f, 0.4f, 0.6f, 0.8f, 1.0f,
     1.2f,  1.4f, 1.6f, 1.8f, 2.1f, 2.4f, 2.8f, 3.3f };

// zeroed region: matchw + posw + candCount + ticketB + globalTicket
static constexpr size_t ZBYTES_ =
    (size_t)B_*WPB_*4*2 + (size_t)B_*CCS_*4*2 + 16;
static constexpr int ZVEC_ = (int)((ZBYTES_ + 15) / 16);

__device__ inline unsigned zmap(float z) {
    const unsigned f = __float_as_uint(z);
    return (f & 0x80000000u) ? ~f : (f | 0x80000000u);
}
__device__ inline float zunmap(unsigned u) {
    const unsigned f = (u & 0x80000000u) ? (u & 0x7FFFFFFFu) : ~u;
    return __uint_as_float(f);
}

// ---------------------------------------------------------------- kernel 0
__global__ __launch_bounds__(256) void k_zero(ulonglong2* __restrict__ dst)
{
    const int i = blockIdx.x*256 + threadIdx.x;
    if (i < ZVEC_) dst[i] = make_ulonglong2(0ull, 0ull);
}

// ---------------------------------------------------------------- kernel 1
// One block per (b,g). Enumerate intersecting priors.
__global__ __launch_bounds__(256) void k_sparse(
    const float4* __restrict__ gt4,      // [B*G] point-form
    const float4* __restrict__ priors4,  // [P]  (cx,cy,w,h)
    unsigned* __restrict__ matchw,       // [B*WPB_], zeroed
    unsigned long long* __restrict__ bp_pack)   // [B*G]
{
    const int g = blockIdx.x;            // G_
    const int b = blockIdx.y;            // B_
    const int bg = b*G_ + g;
    const int tid = threadIdx.x;

    const float4 t = gt4[bg];
    const float area_t = (t.z - t.x) * (t.w - t.y);

    float bv = -1.0f; int bq = 0;

#pragma unroll
    for (int r = 0; r < 6; ++r) {
        const int   f    = (r < 2) ? 105 : (r < 4) ? 53 : 27;
        const float sc   = (r < 2) ? 105.0f : (r < 4) ? 52.5f : 26.25f; // 840/step
        const int   base = (r == 0) ? 0 : (r == 1) ? 11025 : (r == 2) ? 22050
                         : (r == 3) ? 24859 : (r == 4) ? 27668 : 28397;
        const float hw   = ((r == 0) ? 16.0f : (r == 1) ? 32.0f : (r == 2) ? 64.0f
                         : (r == 3) ? 128.0f : (r == 4) ? 256.0f : 512.0f)
                           * (0.5f / 840.0f);

        const int j0 = max(0,     (int)floorf((t.x - hw)*sc - 0.5f) - 1);
        const int j1 = min(f - 1, (int)ceilf ((t.z + hw)*sc - 0.5f) + 1);
        const int i0 = max(0,     (int)floorf((t.y - hw)*sc - 0.5f) - 1);
        const int i1 = min(f - 1, (int)ceilf ((t.w + hw)*sc - 0.5f) + 1);
        const int W = j1 - j0 + 1;
        const int n = W * (i1 - i0 + 1);

        for (int c = tid; c < n; c += 256) {
            const int ii = c / W;
            const int jj = c - ii*W;
            const int p = base + (i0 + ii)*f + (j0 + jj);
            const float4 pr = priors4[p];
            const float hx = pr.z * 0.5f, hy = pr.w * 0.5f;
            const float px0 = pr.x - hx, py0 = pr.y - hy;
            const float px1 = pr.x + hx, py1 = pr.y + hy;
            const float area_p = (px1 - px0) * (py1 - py0);
            const float lx = fmaxf(t.x, px0), ly = fmaxf(t.y, py0);
            const float rx = fminf(t.z, px1), ry = fminf(t.w, py1);
            const float iw = fmaxf(rx - lx, 0.0f), ih = fmaxf(ry - ly, 0.0f);
            const float inter = iw * ih;
            const float iou = __fdividef(inter, (area_t + area_p) - inter);

            if (iou >= THRESH_)
                atomicOr(&matchw[b*WPB_ + (p >> 5)], 1u << (p & 31));
            if (iou > bv) { bv = iou; bq = p; }   // increasing p => min-p tie
        }
    }

    const int lane = tid & 63, wave = tid >> 6;
    for (int m = 32; m; m >>= 1) {
        const float ov = __shfl_xor(bv, m, 64);
        const int   oq = __shfl_xor(bq, m, 64);
        if (ov > bv || (ov == bv && oq < bq)) { bv = ov; bq = oq; }
    }
    __shared__ float swv[4];
    __shared__ int   swq[4];
    if (lane == 0) { swv[wave] = bv; swq[wave] = bq; }
    __syncthreads();
    if (tid == 0) {
        float v = swv[0]; int q = swq[0];
#pragma unroll
        for (int w = 1; w < 4; ++w)
            if (swv[w] > v || (swv[w] == v && swq[w] < q)) { v = swv[w]; q = swq[w]; }
        bp_pack[bg] = (v >= 0.0f)
            ? (((unsigned long long)__float_as_uint(v) << 32)
               | (unsigned long long)(~(unsigned int)q))
            : 0ull;
    }
}

// ---------------------------------------------------------------- kernel 2
// 8 consecutive priors/thread (2048/block): z fast path (no transcendentals),
// rare slow path for positives, z-ladder counts, shuffle-reduce epilogue.
__global__ __launch_bounds__(256) void k_count(
    const float4* __restrict__ loc4,
    const float2* __restrict__ conf2,
    const float4* __restrict__ gt4,
    const int* __restrict__ labels,
    const float4* __restrict__ priors4,
    const unsigned* __restrict__ matchw,
    unsigned* __restrict__ posw,           // [B*WPB_], zeroed
    const unsigned long long* __restrict__ bp_pack,
    float* __restrict__ pl, float* __restrict__ pc, int* __restrict__ pp,
    unsigned int* __restrict__ pcnt)       // [NBL_][8] packed u16 pairs
{
    const int b = blockIdx.y;
    const int tid = threadIdx.x;
    const int lane = tid & 63, wave = tid >> 6;
    const int pbase = blockIdx.x*2048;

    __shared__ float4 sgt[G_];
    __shared__ float  sarea[G_];
    __shared__ int    slab[G_];
    __shared__ int    sovr[2048];
    if (tid < G_) {
        const float4 t = gt4[b*G_ + tid];
        sgt[tid] = t;
        sarea[tid] = (t.z - t.x) * (t.w - t.y);
        slab[tid] = labels[b*G_ + tid];
    }
    for (int i = tid; i < 2048; i += 256) sovr[i] = -1;
    __syncthreads();
    if (tid < G_) {
        const unsigned long long pk = bp_pack[b*G_ + tid];
        const int q = (int)(~(unsigned int)(pk & 0xFFFFFFFFull)) - pbase;
        if (q >= 0 && q < 2048) atomicMax(&sovr[q], tid);  // max g = last-wins
    }
    __syncthreads();

    const int p0 = pbase + tid*8;
    float lL = 0.0f, pce = 0.0f; int np = 0;
    unsigned q0 = 0, q1 = 0, q2 = 0, q3 = 0, q4 = 0, q5 = 0, q6 = 0, q7 = 0;

    if (p0 < P_) {
        const unsigned mw = (matchw[b*WPB_ + (p0 >> 5)] >> (p0 & 31)) & 0xFFu;
        const int4 ovA = *(const int4*)&sovr[tid*8];
        const int4 ovB = *(const int4*)&sovr[tid*8 + 4];
        const int og[8] = { ovA.x, ovA.y, ovA.z, ovA.w,
                            ovB.x, ovB.y, ovB.z, ovB.w };
        const bool full = (p0 + 7 < P_);

        float cf[16];   // conf[p0..p0+7] as 8x(x,y)
        if (full) {
            const float4* c4 = (const float4*)conf2;
            const size_t base2 = ((size_t)b*P_ + p0) >> 1;
            const float4 ca = c4[base2];
            const float4 cb = c4[base2 + 1];
            const float4 cc2 = c4[base2 + 2];
            const float4 cd = c4[base2 + 3];
            cf[0]=ca.x;  cf[1]=ca.y;  cf[2]=ca.z;  cf[3]=ca.w;
            cf[4]=cb.x;  cf[5]=cb.y;  cf[6]=cb.z;  cf[7]=cb.w;
            cf[8]=cc2.x; cf[9]=cc2.y; cf[10]=cc2.z; cf[11]=cc2.w;
            cf[12]=cd.x; cf[13]=cd.y; cf[14]=cd.z;  cf[15]=cd.w;
        } else {
            for (int c = 0; c < 8; ++c) {
                if (p0 + c < P_) {
                    const float2 x = conf2[(size_t)b*P_ + p0 + c];
                    cf[2*c] = x.x; cf[2*c+1] = x.y;
                } else { cf[2*c] = 0.0f; cf[2*c+1] = 0.0f; }
            }
        }

        float z8[8];
#pragma unroll
        for (int c = 0; c < 8; ++c)
            z8[c] = (p0 + c < P_) ? (cf[2*c+1] - cf[2*c])
                                  : -__int_as_float(0x7F800000);  // -inf pad

        unsigned spec = 0;
#pragma unroll
        for (int c = 0; c < 8; ++c)
            if (og[c] >= 0 || ((mw >> c) & 1u)) spec |= (1u << c);

        if (__any(spec != 0u)) {
            unsigned posbits = 0;
#pragma unroll
            for (int c = 0; c < 8; ++c) {
                const int p = p0 + c;
                if (((spec >> c) & 1u) && p < P_) {
                    int cc = 0, g = 0;
                    if (og[c] >= 0) { g = og[c]; cc = slab[g]; }
                    else {
                        // exact dense argmax rescan (bit-identical IoU)
                        const float4 pr = priors4[p];
                        const float hx = pr.z * 0.5f, hy = pr.w * 0.5f;
                        const float px0 = pr.x - hx, py0 = pr.y - hy;
                        const float px1 = pr.x + hx, py1 = pr.y + hy;
                        const float area_p = (px1 - px0) * (py1 - py0);
                        float best = -1.0f;
#pragma unroll
                        for (int gg = 0; gg < G_; ++gg) {
                            const float4 t = sgt[gg];
                            const float lx = fmaxf(t.x, px0), ly = fmaxf(t.y, py0);
                            const float rx = fminf(t.z, px1), ry = fminf(t.w, py1);
                            const float iw = fmaxf(rx - lx, 0.0f), ih = fmaxf(ry - ly, 0.0f);
                            const float inter = iw * ih;
                            const float iou = __fdividef(inter, (sarea[gg] + area_p) - inter);
                            if (iou > best) { best = iou; g = gg; }  // first g on tie
                        }
                        cc = slab[g];
                    }
                    if (cc > 0) {
                        const float ce = __logf(1.0f + __expf(cf[2*c] - cf[2*c+1]));
                        np += 1; pce += ce;
                        z8[c] = -__int_as_float(0x7F800000);   // excluded
                        posbits |= 1u << ((p0 & 31) + c);
                        const float4 t  = sgt[g];
                        const float4 pr = priors4[p];
                        const float gcx = __fdividef((t.x + t.z)*0.5f - pr.x, 0.1f*pr.z);
                        const float gcy = __fdividef((t.y + t.w)*0.5f - pr.y, 0.1f*pr.w);
                        const float gw  = __logf(__fdividef(t.z - t.x, pr.z)) * 5.0f;
                        const float gh  = __logf(__fdividef(t.w - t.y, pr.w)) * 5.0f;
                        const float4 l = loc4[(size_t)b*P_ + p];
                        const float d0 = fabsf(l.x - gcx);
                        const float d1 = fabsf(l.y - gcy);
                        const float d2 = fabsf(l.z - gw);
                        const float d3 = fabsf(l.w - gh);
                        lL += (d0 < 1.0f) ? 0.5f*d0*d0 : d0 - 0.5f;
                        lL += (d1 < 1.0f) ? 0.5f*d1*d1 : d1 - 0.5f;
                        lL += (d2 < 1.0f) ? 0.5f*d2*d2 : d2 - 0.5f;
                        lL += (d3 < 1.0f) ? 0.5f*d3*d3 : d3 - 0.5f;
                    }
                }
            }
            if (posbits) atomicOr(&posw[b*WPB_ + (p0 >> 5)], posbits);
        }

        // z-ladder counts (literals must match LAD_ exactly)
#pragma unroll
        for (int c = 0; c < 8; ++c) {
            const float z = z8[c];
            q0 += (unsigned)(z > -0.5f) + ((unsigned)(z > -0.2f) << 16);
            q1 += (unsigned)(z >  0.0f) + ((unsigned)(z >  0.2f) << 16);
            q2 += (unsigned)(z >  0.4f) + ((unsigned)(z >  0.6f) << 16);
            q3 += (unsigned)(z >  0.8f) + ((unsigned)(z >  1.0f) << 16);
            q4 += (unsigned)(z >  1.2f) + ((unsigned)(z >  1.4f) << 16);
            q5 += (unsigned)(z >  1.6f) + ((unsigned)(z >  1.8f) << 16);
            q6 += (unsigned)(z >  2.1f) + ((unsigned)(z >  2.4f) << 16);
            q7 += (unsigned)(z >  2.8f) + ((unsigned)(z >  3.3f) << 16);
        }
    }

    for (int m = 32; m; m >>= 1) {
        lL  += __shfl_xor(lL, m, 64);
        pce += __shfl_xor(pce, m, 64);
        np  += __shfl_xor(np, m, 64);
        q0 += __shfl_xor(q0, m, 64); q1 += __shfl_xor(q1, m, 64);
        q2 += __shfl_xor(q2, m, 64); q3 += __shfl_xor(q3, m, 64);
        q4 += __shfl_xor(q4, m, 64); q5 += __shfl_xor(q5, m, 64);
        q6 += __shfl_xor(q6, m, 64); q7 += __shfl_xor(q7, m, 64);
    }
    __shared__ float swL[4], swC[4];
    __shared__ int   swP[4];
    __shared__ unsigned swu[4][8];
    if (lane == 0) {
        swL[wave] = lL; swC[wave] = pce; swP[wave] = np;
        swu[wave][0] = q0; swu[wave][1] = q1; swu[wave][2] = q2; swu[wave][3] = q3;
        swu[wave][4] = q4; swu[wave][5] = q5; swu[wave][6] = q6; swu[wave][7] = q7;
    }
    __syncthreads();
    const int o = b*NCH_ + blockIdx.x;
    if (tid == 0) {
        pl[o] = swL[0] + swL[1] + swL[2] + swL[3];
        pc[o] = swC[0] + swC[1] + swC[2] + swC[3];
        pp[o] = swP[0] + swP[1] + swP[2] + swP[3];
    }
    if (tid < 8)
        pcnt[o*8 + tid] = swu[0][tid] + swu[1][tid] + swu[2][tid] + swu[3][tid];
}

// --------------------------------------------------------- bracket helper
__device__ inline void bracket_block(
    const unsigned int* __restrict__ pcnt, const int* __restrict__ pp,
    int b, int tid, int4* out, int* np_out)
{
    __shared__ int sred[256];
    sred[tid] = (tid < NCH_) ? pp[b*NCH_ + tid] : 0;
    __syncthreads();
    for (int off = 128; off > 0; off >>= 1) {
        if (tid < off) sred[tid] += sred[tid+off];
        __syncthreads();
    }
    const int np = sred[0];
    int k = NEGPOS_ * np; if (k > P_-1) k = P_-1;

    __shared__ unsigned red[32][8];
    {
        const int i = tid >> 3, j = tid & 7;
        red[i][j] = (i < NCH_) ? pcnt[(b*NCH_ + i)*8 + j] : 0u;
    }
    __syncthreads();
    for (int off = 16; off > 0; off >>= 1) {
        const int i = tid >> 3, j = tid & 7;
        if (i < off) red[i][j] += red[i+off][j];
        __syncthreads();
    }
    __shared__ int C[16];
    if (tid < 8) {
        C[2*tid]   = (int)(red[0][tid] & 0xFFFFu);
        C[2*tid+1] = (int)(red[0][tid] >> 16);
    }
    __shared__ int4 sbr;
    __syncthreads();
    if (tid == 0) {
        int4 s; s.w = 0;
        if (k <= 0) {
            s.x = 0x7F800000; s.y = 0x7F800000; s.z = 0;      // +inf/+inf
        } else {
            int js = -1;
            for (int j = 0; j < 16; ++j) if (C[j] >= k) js = j;
            if (js < 0) {
                s.x = __float_as_int(LAD_[0]);
                s.y = (int)0xFF800000;                        // lo = -inf
                s.z = k - C[0];
            } else if (js == 15) {
                s.x = 0x7F800000;
                s.y = __float_as_int(LAD_[15]);
                s.z = k;
            } else {
                s.x = __float_as_int(LAD_[js+1]);
                s.y = __float_as_int(LAD_[js]);
                s.z = k - C[js+1];
            }
        }
        sbr = s;
    }
    __syncthreads();
    *out = sbr;
    *np_out = np;
}

// ---------------------------------------------------------------- kernel 3
// 8 priors/thread: bracket in-block; z recompute; sum softplus(z>hi);
// compact candidates; per-batch ticket -> 15th block runs exact radix +
// batch reduce; global ticket -> last finisher writes out[0].
__global__ __launch_bounds__(256) void k_colfin(
    const float2* __restrict__ conf2,
    const unsigned* __restrict__ posw,
    const unsigned int* __restrict__ pcnt, const int* __restrict__ pp,
    const float* __restrict__ pl, const float* __restrict__ pc,
    float* __restrict__ pcol,
    unsigned int* __restrict__ cand, int* __restrict__ candCount,
    int* __restrict__ ticketB, unsigned int* __restrict__ ticketG,
    float4* __restrict__ outb, float* __restrict__ out)
{
    const int b = blockIdx.y;
    const int tid = threadIdx.x;
    const int lane = tid & 63;

    int4 se; int np;
    bracket_block(pcnt, pp, b, tid, &se, &np);
    const float hi = __int_as_float(se.x);
    const float lo = __int_as_float(se.y);
    const int kk = se.z;

    __shared__ unsigned int sbuf[2048];
    __shared__ int scnt;
    __shared__ int gbase;
    if (tid == 0) scnt = 0;
    __syncthreads();

    const int p0 = blockIdx.x*2048 + tid*8;
    float z8[8];
#pragma unroll
    for (int c = 0; c < 8; ++c) z8[c] = -__int_as_float(0x7F800000);
    if (p0 < P_) {
        const unsigned pw = (posw[b*WPB_ + (p0 >> 5)] >> (p0 & 31)) & 0xFFu;
        if (p0 + 7 < P_) {
            const float4* c4 = (const float4*)conf2;
            const size_t base2 = ((size_t)b*P_ + p0) >> 1;
            const float4 ca = c4[base2];
            const float4 cb = c4[base2 + 1];
            const float4 cc2 = c4[base2 + 2];
            const float4 cd = c4[base2 + 3];
            z8[0] = ca.y - ca.x;  z8[1] = ca.w - ca.z;
            z8[2] = cb.y - cb.x;  z8[3] = cb.w - cb.z;
            z8[4] = cc2.y - cc2.x; z8[5] = cc2.w - cc2.z;
            z8[6] = cd.y - cd.x;  z8[7] = cd.w - cd.z;
        } else {
            for (int c = 0; c < 8; ++c) {
                if (p0 + c < P_) {
                    const float2 x = conf2[(size_t)b*P_ + p0 + c];
                    z8[c] = x.y - x.x;
                }
            }
        }
#pragma unroll
        for (int c = 0; c < 8; ++c)
            if ((pw >> c) & 1u) z8[c] = -__int_as_float(0x7F800000);
    }

    float sum = 0.0f;
#pragma unroll
    for (int c = 0; c < 8; ++c) {
        const float z = z8[c];
        bool isCand = false;
        if (z > hi) sum += __logf(1.0f + __expf(z));
        else isCand = (z > lo);
        const unsigned long long mask = __ballot(isCand);
        const int wcnt = __popcll(mask);
        int wbase = 0;
        if (lane == 0 && wcnt) wbase = atomicAdd(&scnt, wcnt);
        wbase = __shfl(wbase, 0, 64);
        if (isCand) {
            const int before = __popcll(mask & ((1ull << lane) - 1ull));
            sbuf[wbase + before] = zmap(z);
        }
    }
    __syncthreads();
    const int tot = scnt;
    if (tid == 0) gbase = tot ? atomicAdd(&candCount[b*CCS_], tot) : 0;
    __syncthreads();
    for (int i = tid; i < tot; i += 256)
        cand[(size_t)b*P_ + gbase + i] = sbuf[i];

    __shared__ float sf2[256];
    sf2[tid] = sum;
    __syncthreads();
    for (int off = 128; off > 0; off >>= 1) {
        if (tid < off) sf2[tid] += sf2[tid+off];
        __syncthreads();
    }
    if (tid == 0) pcol[b*NCH_ + blockIdx.x] = sf2[0];

    // ---- per-batch ticket: last block of this batch finishes the batch
    __shared__ int sdoneB;
    if (tid == 0) {
        __threadfence();
        sdoneB = atomicAdd(&ticketB[b*CCS_], 1);
    }
    __syncthreads();
    if (sdoneB != NCH_ - 1) return;
    __threadfence();   // acquire: see all batch blocks' cand/pcol/candCount

    // reduce pl/pc/pcol (NCH_ entries each)
    __shared__ float rA[256], rB[256], rC2[256];
    rA[tid]  = (tid < NCH_) ? pl[b*NCH_ + tid] : 0.0f;
    rB[tid]  = (tid < NCH_) ? pc[b*NCH_ + tid] : 0.0f;
    rC2[tid] = (tid < NCH_) ? pcol[b*NCH_ + tid] : 0.0f;
    __syncthreads();
    for (int off = 128; off > 0; off >>= 1) {
        if (tid < off) {
            rA[tid] += rA[tid+off];
            rB[tid] += rB[tid+off];
            rC2[tid] += rC2[tid+off];
        }
        __syncthreads();
    }
    const float sumL = rA[0], sumC = rB[0], sumhi = rC2[0];
    __syncthreads();

    float ctopv = sumhi;
    const int nc = candCount[b*CCS_];
    if (kk > 0 && nc > 0) {
        const unsigned int* row = cand + (size_t)b * P_;
        __shared__ unsigned int hist[256];
        __shared__ unsigned int sc0[256], sc1[256];
        __shared__ unsigned int sh_prefix;
        __shared__ int sh_kk;

        unsigned int prefix = 0; int kk2 = kk;
        for (int pass = 3; pass >= 0; --pass) {
            hist[tid] = 0;
            __syncthreads();
            const unsigned int highmask =
                (pass == 3) ? 0u : (0xFFFFFFFFu << ((pass+1)*8));
            for (int i = tid; i < nc; i += 256) {
                const unsigned int u = row[i];
                if ((u & highmask) == (prefix & highmask))
                    atomicAdd(&hist[(u >> (pass*8)) & 255u], 1u);
            }
            __syncthreads();
            sc0[tid] = hist[255 - tid];
            __syncthreads();
            unsigned int* src = sc0; unsigned int* dst = sc1;
            for (int off = 1; off < 256; off <<= 1) {
                unsigned int v = src[tid];
                if (tid >= off) v += src[tid - off];
                dst[tid] = v;
                __syncthreads();
                unsigned int* t2 = src; src = dst; dst = t2;
            }
            {
                const int bin = 255 - tid;
                const int cum = (int)src[tid];
                const int cumPrev = (tid == 0) ? 0 : (int)src[tid-1];
                if (cum >= kk2 && cumPrev < kk2) {
                    sh_prefix = prefix | ((unsigned int)bin << (pass*8));
                    sh_kk = kk2 - cumPrev;
                }
            }
            __syncthreads();
            prefix = sh_prefix; kk2 = sh_kk;
            __syncthreads();
        }

        const float zT = zunmap(prefix);
        const float T = __logf(1.0f + __expf(zT));
        float s2 = 0.0f; int cnt = 0;
        for (int i = tid; i < nc; i += 256) {
            const unsigned int u = row[i];
            if (u > prefix) {
                s2 += __logf(1.0f + __expf(zunmap(u)));
                ++cnt;
            }
        }
        __shared__ float sf[256];
        __shared__ int   sci[256];
        sf[tid] = s2; sci[tid] = cnt;
        __syncthreads();
        for (int off = 128; off > 0; off >>= 1) {
            if (tid < off) { sf[tid] += sf[tid+off]; sci[tid] += sci[tid+off]; }
            __syncthreads();
        }
        ctopv = sumhi + sf[0] + (float)(kk - sci[0]) * T;
    }

    // ---- global ticket: last batch finisher reduces outb -> out[0]
    __shared__ int sdoneG;
    if (tid == 0) {
        outb[b] = make_float4(sumL, sumC, (float)np, ctopv);
        __threadfence();
        sdoneG = (int)atomicAdd(ticketG, 1u);
    }
    __syncthreads();
    if (sdoneG == B_ - 1) {
        __threadfence();
        float L = 0.0f, C = 0.0f, Pn = 0.0f, T = 0.0f;
        if (tid < B_) {
            const float4 v = outb[tid];
            L = v.x; C = v.y; Pn = v.z; T = v.w;
        }
        for (int m = 32; m; m >>= 1) {
            L += __shfl_xor(L, m, 64);
            C += __shfl_xor(C, m, 64);
            Pn += __shfl_xor(Pn, m, 64);
            T += __shfl_xor(T, m, 64);
        }
        if (tid == 0)
            out[0] = (2.0f*L + C + T) / fmaxf(Pn, 1.0f);
    }
}

// ----------------------------------------------------------------
extern "C" void kernel_launch(void* const* d_in, const int* in_sizes, int n_in,
                              void* d_out, int out_size, void* d_ws, size_t ws_size,
                              hipStream_t stream)
{
    const float* loc    = (const float*)d_in[0];   // [B,P,4]
    const float* conf   = (const float*)d_in[1];   // [B,P,2]
    const float* gt     = (const float*)d_in[2];   // [B,G,4]
    const int*   labels = (const int*)d_in[3];     // [B,G]
    const float* priors = (const float*)d_in[4];   // [P,4]
    float* out = (float*)d_out;

    char* ws = (char*)d_ws;
    size_t off = 0;
    // --- zeroed region (filled by k_zero) ---
    unsigned* matchw = (unsigned*)(ws + off);        off += (size_t)B_*WPB_*4;
    unsigned* posw   = (unsigned*)(ws + off);        off += (size_t)B_*WPB_*4;
    int* candCount = (int*)(ws + off);               off += (size_t)B_*CCS_*4;
    int* ticketB   = (int*)(ws + off);               off += (size_t)B_*CCS_*4;
    unsigned int* ticketG = (unsigned int*)(ws + off); off += 16;
    // --- rest ---
    off = (off + 255) & ~255ull;
    unsigned long long* bp_pack =
        (unsigned long long*)(ws + off);             off += (size_t)B_*G_*8;
    float* pl   = (float*)(ws + off);                off += (size_t)NBL_*4;
    float* pc   = (float*)(ws + off);                off += (size_t)NBL_*4;
    int*   pp   = (int*)(ws + off);                  off += (size_t)NBL_*4;
    float* pcol = (float*)(ws + off);                off += (size_t)NBL_*4;
    unsigned int* pcnt = (unsigned int*)(ws + off);  off += (size_t)NBL_*8*4;
    unsigned int* cand = (unsigned int*)(ws + off);  off += (size_t)B_*P_*4;
    float4* outb = (float4*)(ws + off);              off += (size_t)B_*16;

    k_zero<<<dim3((ZVEC_ + 255)/256), dim3(256), 0, stream>>>((ulonglong2*)ws);
    k_sparse<<<dim3(G_, B_), dim3(256), 0, stream>>>(
        (const float4*)gt, (const float4*)priors, matchw, bp_pack);
    k_count<<<dim3(NCH_, B_), dim3(256), 0, stream>>>(
        (const float4*)loc, (const float2*)conf, (const float4*)gt, labels,
        (const float4*)priors, matchw, posw, bp_pack, pl, pc, pp, pcnt);
    k_colfin<<<dim3(NCH_, B_), dim3(256), 0, stream>>>(
        (const float2*)conf, posw, pcnt, pp, pl, pc, pcol,
        cand, candCount, ticketB, ticketG, outb, out);
}

// Round 21
// 73.054 us; speedup vs baseline: 1.5468x; 1.5468x over previous
//
#include <hip/hip_runtime.h>

// SSD MultiBoxLoss: B=64, P=29126, G=24, 2 classes, scalar fp32 output.
// z-space selection: CE = softplus(z) is monotone in z = other-gold, so
// top-k by z == top-k by CE (sum is tie-invariant). Hot loop has NO
// transcendentals and NO mine buffer; softplus evaluated only for the
// ~k selected elements at collect/select time. Exact.
static constexpr int B_ = 64;
static constexpr int P_ = 29126;
static constexpr int G_ = 24;
static constexpr float THRESH_ = 0.35f;
static constexpr int NEGPOS_ = 7;
static constexpr int PBL_ = (P_ + 1023) / 1024;   // 29 p-blocks (1024 each)
static constexpr int NBL_ = PBL_ * B_;            // 1856 partial slots
static constexpr int WPB_ = 912;                  // bit-words/batch
static constexpr int CCS_ = 32;                   // candCount stride = 128 B

// z-space ladder (must match literals in k_count exactly)
__device__ const float LAD_[16] = {
    -0.5f, -0.2f, 0.0f, 0.2f, 0.4f, 0.6f, 0.8f, 1.0f,
     1.2f,  1.4f, 1.6f, 1.8f, 2.1f, 2.4f, 2.8f, 3.3f };

// zeroed region: matchw + posw + candCount + ticket
static constexpr size_t ZBYTES_ =
    (size_t)B_*WPB_*4*2 + (size_t)B_*CCS_*4 + 16;
static constexpr int ZVEC_ = (int)((ZBYTES_ + 15) / 16);

__device__ inline unsigned zmap(float z) {
    const unsigned f = __float_as_uint(z);
    return (f & 0x80000000u) ? ~f : (f | 0x80000000u);
}
__device__ inline float zunmap(unsigned u) {
    const unsigned f = (u & 0x80000000u) ? (u & 0x7FFFFFFFu) : ~u;
    return __uint_as_float(f);
}

// ---------------------------------------------------------------- kernel 0
__global__ __launch_bounds__(256) void k_zero(ulonglong2* __restrict__ dst)
{
    const int i = blockIdx.x*256 + threadIdx.x;
    if (i < ZVEC_) dst[i] = make_ulonglong2(0ull, 0ull);
}

// ---------------------------------------------------------------- kernel 1
// One block per (b,g). Enumerate intersecting priors.
__global__ __launch_bounds__(256) void k_sparse(
    const float4* __restrict__ gt4,      // [B*G] point-form
    const float4* __restrict__ priors4,  // [P]  (cx,cy,w,h)
    unsigned* __restrict__ matchw,       // [B*WPB_], zeroed
    unsigned long long* __restrict__ bp_pack)   // [B*G]
{
    const int g = blockIdx.x;            // G_
    const int b = blockIdx.y;            // B_
    const int bg = b*G_ + g;
    const int tid = threadIdx.x;

    const float4 t = gt4[bg];
    const float area_t = (t.z - t.x) * (t.w - t.y);

    float bv = -1.0f; int bq = 0;

#pragma unroll
    for (int r = 0; r < 6; ++r) {
        const int   f    = (r < 2) ? 105 : (r < 4) ? 53 : 27;
        const float sc   = (r < 2) ? 105.0f : (r < 4) ? 52.5f : 26.25f; // 840/step
        const int   base = (r == 0) ? 0 : (r == 1) ? 11025 : (r == 2) ? 22050
                         : (r == 3) ? 24859 : (r == 4) ? 27668 : 28397;
        const float hw   = ((r == 0) ? 16.0f : (r == 1) ? 32.0f : (r == 2) ? 64.0f
                         : (r == 3) ? 128.0f : (r == 4) ? 256.0f : 512.0f)
                           * (0.5f / 840.0f);

        const int j0 = max(0,     (int)floorf((t.x - hw)*sc - 0.5f) - 1);
        const int j1 = min(f - 1, (int)ceilf ((t.z + hw)*sc - 0.5f) + 1);
        const int i0 = max(0,     (int)floorf((t.y - hw)*sc - 0.5f) - 1);
        const int i1 = min(f - 1, (int)ceilf ((t.w + hw)*sc - 0.5f) + 1);
        const int W = j1 - j0 + 1;
        const int n = W * (i1 - i0 + 1);

        for (int c = tid; c < n; c += 256) {
            const int ii = c / W;
            const int jj = c - ii*W;
            const int p = base + (i0 + ii)*f + (j0 + jj);
            const float4 pr = priors4[p];
            const float hx = pr.z * 0.5f, hy = pr.w * 0.5f;
            const float px0 = pr.x - hx, py0 = pr.y - hy;
            const float px1 = pr.x + hx, py1 = pr.y + hy;
            const float area_p = (px1 - px0) * (py1 - py0);
            const float lx = fmaxf(t.x, px0), ly = fmaxf(t.y, py0);
            const float rx = fminf(t.z, px1), ry = fminf(t.w, py1);
            const float iw = fmaxf(rx - lx, 0.0f), ih = fmaxf(ry - ly, 0.0f);
            const float inter = iw * ih;
            const float iou = __fdividef(inter, (area_t + area_p) - inter);

            if (iou >= THRESH_)
                atomicOr(&matchw[b*WPB_ + (p >> 5)], 1u << (p & 31));
            if (iou > bv) { bv = iou; bq = p; }   // increasing p => min-p tie
        }
    }

    const int lane = tid & 63, wave = tid >> 6;
    for (int m = 32; m; m >>= 1) {
        const float ov = __shfl_xor(bv, m, 64);
        const int   oq = __shfl_xor(bq, m, 64);
        if (ov > bv || (ov == bv && oq < bq)) { bv = ov; bq = oq; }
    }
    __shared__ float swv[4];
    __shared__ int   swq[4];
    if (lane == 0) { swv[wave] = bv; swq[wave] = bq; }
    __syncthreads();
    if (tid == 0) {
        float v = swv[0]; int q = swq[0];
#pragma unroll
        for (int w = 1; w < 4; ++w)
            if (swv[w] > v || (swv[w] == v && swq[w] < q)) { v = swv[w]; q = swq[w]; }
        bp_pack[bg] = (v >= 0.0f)
            ? (((unsigned long long)__float_as_uint(v) << 32)
               | (unsigned long long)(~(unsigned int)q))
            : 0ull;
    }
}

// ---------------------------------------------------------------- kernel 2
// 4 consecutive priors/thread: z = other-gold (NO transcendentals in fast
// path); rare slow path (override/matched) computes pos CE + smooth-L1 and
// sets posw bit; z-ladder counts; shuffle-reduce epilogue. No mine buffer.
__global__ __launch_bounds__(256) void k_count(
    const float4* __restrict__ loc4,
    const float2* __restrict__ conf2,
    const float4* __restrict__ gt4,
    const int* __restrict__ labels,
    const float4* __restrict__ priors4,
    const unsigned* __restrict__ matchw,
    unsigned* __restrict__ posw,           // [B*WPB_], zeroed
    const unsigned long long* __restrict__ bp_pack,
    float* __restrict__ pl, float* __restrict__ pc, int* __restrict__ pp,
    unsigned int* __restrict__ pcnt)       // [NBL_][8] packed u16 pairs
{
    const int b = blockIdx.y;
    const int tid = threadIdx.x;
    const int lane = tid & 63, wave = tid >> 6;
    const int pbase = blockIdx.x*1024;

    __shared__ float4 sgt[G_];
    __shared__ float  sarea[G_];
    __shared__ int    slab[G_];
    __shared__ int    sovr[1024];
    if (tid < G_) {
        const float4 t = gt4[b*G_ + tid];
        sgt[tid] = t;
        sarea[tid] = (t.z - t.x) * (t.w - t.y);
        slab[tid] = labels[b*G_ + tid];
    }
    for (int i = tid; i < 1024; i += 256) sovr[i] = -1;
    __syncthreads();
    if (tid < G_) {
        const unsigned long long pk = bp_pack[b*G_ + tid];
        const int q = (int)(~(unsigned int)(pk & 0xFFFFFFFFull)) - pbase;
        if (q >= 0 && q < 1024) atomicMax(&sovr[q], tid);  // max g = last-wins
    }
    __syncthreads();

    const int p0 = pbase + tid*4;
    float lL = 0.0f, pce = 0.0f; int np = 0;
    unsigned q0 = 0, q1 = 0, q2 = 0, q3 = 0, q4 = 0, q5 = 0, q6 = 0, q7 = 0;

    if (p0 < P_) {
        const unsigned mw = (matchw[b*WPB_ + (p0 >> 5)] >> (p0 & 31)) & 0xFu;
        const int4 ov4 = *(const int4*)&sovr[tid*4];
        const int og[4] = { ov4.x, ov4.y, ov4.z, ov4.w };
        const bool full = (p0 + 3 < P_);

        float cf[8];   // conf[p0..p0+3] as 4x(x,y)
        if (full) {
            const float4* c4 = (const float4*)conf2;
            const size_t base2 = ((size_t)b*P_ + p0) >> 1;
            const float4 ca = c4[base2];
            const float4 cb = c4[base2 + 1];
            cf[0]=ca.x; cf[1]=ca.y; cf[2]=ca.z; cf[3]=ca.w;
            cf[4]=cb.x; cf[5]=cb.y; cf[6]=cb.z; cf[7]=cb.w;
        } else {
            for (int c = 0; c < 4; ++c) {
                if (p0 + c < P_) {
                    const float2 x = conf2[(size_t)b*P_ + p0 + c];
                    cf[2*c] = x.x; cf[2*c+1] = x.y;
                } else { cf[2*c] = -1e30f; cf[2*c+1] = -1e30f; }
            }
        }

        // fast path: z = background CE argument (monotone proxy)
        float z4[4];
#pragma unroll
        for (int c = 0; c < 4; ++c)
            z4[c] = (p0 + c < P_) ? (cf[2*c+1] - cf[2*c])
                                  : -__int_as_float(0x7F800000);  // -inf pad

        unsigned spec = 0;
#pragma unroll
        for (int c = 0; c < 4; ++c)
            if (og[c] >= 0 || ((mw >> c) & 1u)) spec |= (1u << c);

        if (__any(spec != 0u)) {
            unsigned posbits = 0;
#pragma unroll
            for (int c = 0; c < 4; ++c) {
                const int p = p0 + c;
                if (((spec >> c) & 1u) && p < P_) {
                    int cc = 0, g = 0;
                    if (og[c] >= 0) { g = og[c]; cc = slab[g]; }
                    else {
                        // exact dense argmax rescan (bit-identical IoU)
                        const float4 pr = priors4[p];
                        const float hx = pr.z * 0.5f, hy = pr.w * 0.5f;
                        const float px0 = pr.x - hx, py0 = pr.y - hy;
                        const float px1 = pr.x + hx, py1 = pr.y + hy;
                        const float area_p = (px1 - px0) * (py1 - py0);
                        float best = -1.0f;
#pragma unroll
                        for (int gg = 0; gg < G_; ++gg) {
                            const float4 t = sgt[gg];
                            const float lx = fmaxf(t.x, px0), ly = fmaxf(t.y, py0);
                            const float rx = fminf(t.z, px1), ry = fminf(t.w, py1);
                            const float iw = fmaxf(rx - lx, 0.0f), ih = fmaxf(ry - ly, 0.0f);
                            const float inter = iw * ih;
                            const float iou = __fdividef(inter, (sarea[gg] + area_p) - inter);
                            if (iou > best) { best = iou; g = gg; }  // first g on tie
                        }
                        cc = slab[g];
                    }
                    if (cc > 0) {
                        const float ce = __logf(1.0f + __expf(cf[2*c] - cf[2*c+1]));
                        np += 1; pce += ce;
                        z4[c] = -__int_as_float(0x7F800000);   // -inf: excluded
                        posbits |= (1u << (p0 & 31)) << c;
                        const float4 t  = sgt[g];
                        const float4 pr = priors4[p];
                        const float gcx = __fdividef((t.x + t.z)*0.5f - pr.x, 0.1f*pr.z);
                        const float gcy = __fdividef((t.y + t.w)*0.5f - pr.y, 0.1f*pr.w);
                        const float gw  = __logf(__fdividef(t.z - t.x, pr.z)) * 5.0f;
                        const float gh  = __logf(__fdividef(t.w - t.y, pr.w)) * 5.0f;
                        const float4 l = loc4[(size_t)b*P_ + p];
                        const float d0 = fabsf(l.x - gcx);
                        const float d1 = fabsf(l.y - gcy);
                        const float d2 = fabsf(l.z - gw);
                        const float d3 = fabsf(l.w - gh);
                        lL += (d0 < 1.0f) ? 0.5f*d0*d0 : d0 - 0.5f;
                        lL += (d1 < 1.0f) ? 0.5f*d1*d1 : d1 - 0.5f;
                        lL += (d2 < 1.0f) ? 0.5f*d2*d2 : d2 - 0.5f;
                        lL += (d3 < 1.0f) ? 0.5f*d3*d3 : d3 - 0.5f;
                    }
                }
            }
            if (posbits) atomicOr(&posw[b*WPB_ + (p0 >> 5)], posbits);
        }

        // z-ladder counts (literals must match LAD_ exactly)
#pragma unroll
        for (int c = 0; c < 4; ++c) {
            const float z = z4[c];
            q0 += (unsigned)(z > -0.5f) + ((unsigned)(z > -0.2f) << 16);
            q1 += (unsigned)(z >  0.0f) + ((unsigned)(z >  0.2f) << 16);
            q2 += (unsigned)(z >  0.4f) + ((unsigned)(z >  0.6f) << 16);
            q3 += (unsigned)(z >  0.8f) + ((unsigned)(z >  1.0f) << 16);
            q4 += (unsigned)(z >  1.2f) + ((unsigned)(z >  1.4f) << 16);
            q5 += (unsigned)(z >  1.6f) + ((unsigned)(z >  1.8f) << 16);
            q6 += (unsigned)(z >  2.1f) + ((unsigned)(z >  2.4f) << 16);
            q7 += (unsigned)(z >  2.8f) + ((unsigned)(z >  3.3f) << 16);
        }
    }

    for (int m = 32; m; m >>= 1) {
        lL  += __shfl_xor(lL, m, 64);
        pce += __shfl_xor(pce, m, 64);
        np  += __shfl_xor(np, m, 64);
        q0 += __shfl_xor(q0, m, 64); q1 += __shfl_xor(q1, m, 64);
        q2 += __shfl_xor(q2, m, 64); q3 += __shfl_xor(q3, m, 64);
        q4 += __shfl_xor(q4, m, 64); q5 += __shfl_xor(q5, m, 64);
        q6 += __shfl_xor(q6, m, 64); q7 += __shfl_xor(q7, m, 64);
    }
    __shared__ float swL[4], swC[4];
    __shared__ int   swP[4];
    __shared__ unsigned swu[4][8];
    if (lane == 0) {
        swL[wave] = lL; swC[wave] = pce; swP[wave] = np;
        swu[wave][0] = q0; swu[wave][1] = q1; swu[wave][2] = q2; swu[wave][3] = q3;
        swu[wave][4] = q4; swu[wave][5] = q5; swu[wave][6] = q6; swu[wave][7] = q7;
    }
    __syncthreads();
    const int o = b*PBL_ + blockIdx.x;
    if (tid == 0) {
        pl[o] = swL[0] + swL[1] + swL[2] + swL[3];
        pc[o] = swC[0] + swC[1] + swC[2] + swC[3];
        pp[o] = swP[0] + swP[1] + swP[2] + swP[3];
    }
    if (tid < 8)
        pcnt[o*8 + tid] = swu[0][tid] + swu[1][tid] + swu[2][tid] + swu[3][tid];
}

// --------------------------------------------------------- bracket helper
__device__ inline void bracket_block(
    const unsigned int* __restrict__ pcnt, const int* __restrict__ pp,
    int b, int tid, int4* out, int* np_out)
{
    __shared__ int sred[256];
    sred[tid] = (tid < PBL_) ? pp[b*PBL_ + tid] : 0;
    __syncthreads();
    for (int off = 128; off > 0; off >>= 1) {
        if (tid < off) sred[tid] += sred[tid+off];
        __syncthreads();
    }
    const int np = sred[0];
    int k = NEGPOS_ * np; if (k > P_-1) k = P_-1;

    __shared__ unsigned red[32][8];
    {
        const int i = tid >> 3, j = tid & 7;
        red[i][j] = (i < PBL_) ? pcnt[(b*PBL_ + i)*8 + j] : 0u;
    }
    __syncthreads();
    for (int off = 16; off > 0; off >>= 1) {
        const int i = tid >> 3, j = tid & 7;
        if (i < off) red[i][j] += red[i+off][j];
        __syncthreads();
    }
    __shared__ int C[16];
    if (tid < 8) {
        C[2*tid]   = (int)(red[0][tid] & 0xFFFFu);
        C[2*tid+1] = (int)(red[0][tid] >> 16);
    }
    __shared__ int4 sbr;
    __syncthreads();
    if (tid == 0) {
        int4 s; s.w = 0;
        if (k <= 0) {
            s.x = 0x7F800000; s.y = 0x7F800000; s.z = 0;      // +inf/+inf
        } else {
            int js = -1;
            for (int j = 0; j < 16; ++j) if (C[j] >= k) js = j;
            if (js < 0) {
                s.x = __float_as_int(LAD_[0]);
                s.y = (int)0xFF800000;                        // lo = -inf
                s.z = k - C[0];
            } else if (js == 15) {
                s.x = 0x7F800000;
                s.y = __float_as_int(LAD_[15]);
                s.z = k;
            } else {
                s.x = __float_as_int(LAD_[js+1]);
                s.y = __float_as_int(LAD_[js]);
                s.z = k - C[js+1];
            }
        }
        sbr = s;
    }
    __syncthreads();
    *out = sbr;
    *np_out = np;
}

// ---------------------------------------------------------------- kernel 3
// 4 consecutive priors/thread: bracket in-block; recompute z from conf;
// sum softplus(z) for z > hi; compact candidates (lo < z <= hi) as mapped
// u32 via ballot -> LDS -> ONE global atomic per block.
__global__ __launch_bounds__(256) void k_collect(
    const float2* __restrict__ conf2,
    const unsigned* __restrict__ posw,
    const unsigned int* __restrict__ pcnt, const int* __restrict__ pp,
    unsigned int* __restrict__ cand, int* __restrict__ candCount,
    float* __restrict__ pcol)
{
    const int b = blockIdx.y;
    const int tid = threadIdx.x;
    const int lane = tid & 63;

    int4 se; int np_dummy;
    bracket_block(pcnt, pp, b, tid, &se, &np_dummy);
    const float hi = __int_as_float(se.x);
    const float lo = __int_as_float(se.y);

    __shared__ unsigned int sbuf[1024];
    __shared__ int scnt;
    __shared__ int gbase;
    if (tid == 0) scnt = 0;
    __syncthreads();

    const int p0 = blockIdx.x*1024 + tid*4;
    float z4[4] = { -__int_as_float(0x7F800000), -__int_as_float(0x7F800000),
                    -__int_as_float(0x7F800000), -__int_as_float(0x7F800000) };
    if (p0 < P_) {
        const unsigned pw = (posw[b*WPB_ + (p0 >> 5)] >> (p0 & 31)) & 0xFu;
        if (p0 + 3 < P_) {
            const float4* c4 = (const float4*)conf2;
            const size_t base2 = ((size_t)b*P_ + p0) >> 1;
            const float4 ca = c4[base2];
            const float4 cb = c4[base2 + 1];
            z4[0] = ca.y - ca.x; z4[1] = ca.w - ca.z;
            z4[2] = cb.y - cb.x; z4[3] = cb.w - cb.z;
        } else {
            for (int c = 0; c < 4; ++c) {
                if (p0 + c < P_) {
                    const float2 x = conf2[(size_t)b*P_ + p0 + c];
                    z4[c] = x.y - x.x;
                }
            }
        }
#pragma unroll
        for (int c = 0; c < 4; ++c)
            if ((pw >> c) & 1u) z4[c] = -__int_as_float(0x7F800000);
    }

    float sum = 0.0f;
#pragma unroll
    for (int c = 0; c < 4; ++c) {
        const float z = z4[c];
        bool isCand = false;
        if (z > hi) sum += __logf(1.0f + __expf(z));
        else isCand = (z > lo);          // -inf: never (even vs lo=-inf)
        const unsigned long long mask = __ballot(isCand);
        const int wcnt = __popcll(mask);
        int wbase = 0;
        if (lane == 0 && wcnt) wbase = atomicAdd(&scnt, wcnt);
        wbase = __shfl(wbase, 0, 64);
        if (isCand) {
            const int before = __popcll(mask & ((1ull << lane) - 1ull));
            sbuf[wbase + before] = zmap(z);
        }
    }
    __syncthreads();
    const int tot = scnt;
    if (tid == 0) gbase = tot ? atomicAdd(&candCount[b*CCS_], tot) : 0;
    __syncthreads();
    for (int i = tid; i < tot; i += 256)
        cand[(size_t)b*P_ + gbase + i] = sbuf[i];

    __shared__ float sf2[256];
    sf2[tid] = sum;
    __syncthreads();
    for (int off = 128; off > 0; off >>= 1) {
        if (tid < off) sf2[tid] += sf2[tid+off];
        __syncthreads();
    }
    if (tid == 0) pcol[b*PBL_ + blockIdx.x] = sf2[0];
}

// ---------------------------------------------------------------- kernel 4
// Per batch: bracket recompute, pl/pc/pcol reduce, exact radix over mapped
// candidates, softplus sums; LAST block (ticket) reduces outb -> out[0].
__global__ __launch_bounds__(256) void k_sel2fin(
    const unsigned int* __restrict__ cand, const int* __restrict__ candCount,
    const unsigned int* __restrict__ pcnt, const int* __restrict__ pp,
    const float* __restrict__ pl, const float* __restrict__ pc,
    const float* __restrict__ pcol,
    float4* __restrict__ outb, unsigned int* __restrict__ ticket,
    float* __restrict__ out)
{
    const int b = blockIdx.x;
    const int tid = threadIdx.x;

    int4 se; int np;
    bracket_block(pcnt, pp, b, tid, &se, &np);
    const int kk = se.z;

    __shared__ float rA[256], rB[256], rC2[256];
    rA[tid]  = (tid < PBL_) ? pl[b*PBL_ + tid] : 0.0f;
    rB[tid]  = (tid < PBL_) ? pc[b*PBL_ + tid] : 0.0f;
    rC2[tid] = (tid < PBL_) ? pcol[b*PBL_ + tid] : 0.0f;
    __syncthreads();
    for (int off = 128; off > 0; off >>= 1) {
        if (tid < off) {
            rA[tid] += rA[tid+off];
            rB[tid] += rB[tid+off];
            rC2[tid] += rC2[tid+off];
        }
        __syncthreads();
    }
    const float sumL = rA[0], sumC = rB[0], sumhi = rC2[0];
    __syncthreads();

    float ctopv = sumhi;
    const int nc = candCount[b*CCS_];
    if (kk > 0 && nc > 0) {
        const unsigned int* row = cand + (size_t)b * P_;
        __shared__ unsigned int hist[256];
        __shared__ unsigned int sc0[256], sc1[256];
        __shared__ unsigned int sh_prefix;
        __shared__ int sh_kk;

        unsigned int prefix = 0; int kk2 = kk;
        for (int pass = 3; pass >= 0; --pass) {
            hist[tid] = 0;
            __syncthreads();
            const unsigned int highmask =
                (pass == 3) ? 0u : (0xFFFFFFFFu << ((pass+1)*8));
            for (int i = tid; i < nc; i += 256) {
                const unsigned int u = row[i];
                if ((u & highmask) == (prefix & highmask))
                    atomicAdd(&hist[(u >> (pass*8)) & 255u], 1u);
            }
            __syncthreads();
            sc0[tid] = hist[255 - tid];
            __syncthreads();
            unsigned int* src = sc0; unsigned int* dst = sc1;
            for (int off = 1; off < 256; off <<= 1) {
                unsigned int v = src[tid];
                if (tid >= off) v += src[tid - off];
                dst[tid] = v;
                __syncthreads();
                unsigned int* t2 = src; src = dst; dst = t2;
            }
            {
                const int bin = 255 - tid;
                const int cum = (int)src[tid];
                const int cumPrev = (tid == 0) ? 0 : (int)src[tid-1];
                if (cum >= kk2 && cumPrev < kk2) {
                    sh_prefix = prefix | ((unsigned int)bin << (pass*8));
                    sh_kk = kk2 - cumPrev;
                }
            }
            __syncthreads();
            prefix = sh_prefix; kk2 = sh_kk;
            __syncthreads();
        }

        const float zT = zunmap(prefix);
        const float T = __logf(1.0f + __expf(zT));
        float sum = 0.0f; int cnt = 0;
        for (int i = tid; i < nc; i += 256) {
            const unsigned int u = row[i];
            if (u > prefix) {
                sum += __logf(1.0f + __expf(zunmap(u)));
                ++cnt;
            }
        }
        __shared__ float sf[256];
        __shared__ int   sci[256];
        sf[tid] = sum; sci[tid] = cnt;
        __syncthreads();
        for (int off = 128; off > 0; off >>= 1) {
            if (tid < off) { sf[tid] += sf[tid+off]; sci[tid] += sci[tid+off]; }
            __syncthreads();
        }
        ctopv = sumhi + sf[0] + (float)(kk - sci[0]) * T;
    }

    __shared__ int sdone;
    if (tid == 0) {
        outb[b] = make_float4(sumL, sumC, (float)np, ctopv);
        __threadfence();
        sdone = (int)atomicAdd(ticket, 1u);
    }
    __syncthreads();
    if (sdone == B_ - 1) {
        __threadfence();
        float L = 0.0f, C = 0.0f, Pn = 0.0f, T = 0.0f;
        if (tid < B_) {
            const float4 v = outb[tid];
            L = v.x; C = v.y; Pn = v.z; T = v.w;
        }
        for (int m = 32; m; m >>= 1) {
            L += __shfl_xor(L, m, 64);
            C += __shfl_xor(C, m, 64);
            Pn += __shfl_xor(Pn, m, 64);
            T += __shfl_xor(T, m, 64);
        }
        if (tid == 0)
            out[0] = (2.0f*L + C + T) / fmaxf(Pn, 1.0f);
    }
}

// ----------------------------------------------------------------
extern "C" void kernel_launch(void* const* d_in, const int* in_sizes, int n_in,
                              void* d_out, int out_size, void* d_ws, size_t ws_size,
                              hipStream_t stream)
{
    const float* loc    = (const float*)d_in[0];   // [B,P,4]
    const float* conf   = (const float*)d_in[1];   // [B,P,2]
    const float* gt     = (const float*)d_in[2];   // [B,G,4]
    const int*   labels = (const int*)d_in[3];     // [B,G]
    const float* priors = (const float*)d_in[4];   // [P,4]
    float* out = (float*)d_out;

    char* ws = (char*)d_ws;
    size_t off = 0;
    // --- zeroed region (filled by k_zero) ---
    unsigned* matchw = (unsigned*)(ws + off);        off += (size_t)B_*WPB_*4;
    unsigned* posw   = (unsigned*)(ws + off);        off += (size_t)B_*WPB_*4;
    int* candCount = (int*)(ws + off);               off += (size_t)B_*CCS_*4;
    unsigned int* ticket = (unsigned int*)(ws + off); off += 16;
    // --- rest ---
    off = (off + 255) & ~255ull;
    unsigned long long* bp_pack =
        (unsigned long long*)(ws + off);             off += (size_t)B_*G_*8;
    float* pl   = (float*)(ws + off);                off += (size_t)NBL_*4;
    float* pc   = (float*)(ws + off);                off += (size_t)NBL_*4;
    int*   pp   = (int*)(ws + off);                  off += (size_t)NBL_*4;
    float* pcol = (float*)(ws + off);                off += (size_t)NBL_*4;
    unsigned int* pcnt = (unsigned int*)(ws + off);  off += (size_t)NBL_*8*4;
    unsigned int* cand = (unsigned int*)(ws + off);  off += (size_t)B_*P_*4;
    float4* outb = (float4*)(ws + off);              off += (size_t)B_*16;

    k_zero<<<dim3((ZVEC_ + 255)/256), dim3(256), 0, stream>>>((ulonglong2*)ws);
    k_sparse<<<dim3(G_, B_), dim3(256), 0, stream>>>(
        (const float4*)gt, (const float4*)priors, matchw, bp_pack);
    k_count<<<dim3(PBL_, B_), dim3(256), 0, stream>>>(
        (const float4*)loc, (const float2*)conf, (const float4*)gt, labels,
        (const float4*)priors, matchw, posw, bp_pack, pl, pc, pp, pcnt);
    k_collect<<<dim3(PBL_, B_), dim3(256), 0, stream>>>(
        (const float2*)conf, posw, pcnt, pp, cand, candCount, pcol);
    k_sel2fin<<<dim3(B_), dim3(256), 0, stream>>>(
        cand, candCount, pcnt, pp, pl, pc, pcol, outb, ticket, out);
}